// Round 5
// baseline (1137.206 us; speedup 1.0000x reference)
//
#include <hip/hip_runtime.h>
#include <hip/hip_bf16.h>
#include <hip/hip_cooperative_groups.h>

namespace cg = cooperative_groups;

#define NRBF 20
#define KAUG 24   // 20 rbf + env(bias row) + 3 zero pad, stored f16

typedef __attribute__((ext_vector_type(8))) short short8;
typedef __attribute__((ext_vector_type(4))) float float4v;
typedef __attribute__((ext_vector_type(2))) _Float16 half2v;
typedef unsigned short ushort_t;

__device__ __forceinline__ float bf2f(ushort_t u) {
    return __uint_as_float(((unsigned)u) << 16);
}
__device__ __forceinline__ ushort_t f2bf(float f) {
    unsigned u = __float_as_uint(f);
    u += 0x7FFF + ((u >> 16) & 1);   // round-to-nearest-even
    return (ushort_t)(u >> 16);
}
__device__ __forceinline__ float ldin(const void* p, size_t idx, int isbf) {
    return isbf ? bf2f(((const ushort_t*)p)[idx]) : ((const float*)p)[idx];
}
__device__ __forceinline__ void stout(void* p, size_t idx, float v, int isbf) {
    if (isbf) ((ushort_t*)p)[idx] = f2bf(v);
    else      ((float*)p)[idx] = v;
}
__device__ __forceinline__ float dot2(half2v a, half2v b, float c) {
#if __has_builtin(__builtin_amdgcn_fdot2)
    return __builtin_amdgcn_fdot2(a, b, c, false);
#else
    return c + (float)a.x * (float)b.x + (float)a.y * (float)b.y;
#endif
}

// view a 16B float4 register quad as 4 half2 lanes (free re-alias, no moves)
union F4H {
    float4v f;
    half2v  h[4];
};

struct KParams {
    const void* xyz; const int* nbr; const void* cg_s;
    const void* W1;  const void* b1; const void* W2; const void* b2;
    const void* Wr;  const void* br;
    int* flag; float* s_acc; float* vA; float* vB;
    int* rowptr; int* deg; int* jlist; float4* upos;
    _Float16* rbfh; _Float16* WrT;
    ushort_t* s_hi; ushort_t* s_lo; ushort_t* h_hi; ushort_t* h_lo;
    ushort_t* phi;  ushort_t* vhA;  ushort_t* vhB;
    ushort_t* B1hi; ushort_t* B1lo; ushort_t* B2hi; ushort_t* B2lo;
    void* out; int N, E, gx;
};

// ---------------- P0: dtype detect + deg zero ----------------
__device__ __forceinline__ void phase_detect(const KParams& p) {
    int tid = threadIdx.x;
    for (int idx = blockIdx.x * 256 + tid; idx < p.N; idx += gridDim.x * 256)
        p.deg[idx] = 0;
    if (blockIdx.x == 0 && tid < 64) {
        const ushort_t* u = (const ushort_t*)p.xyz;
        unsigned e0 = (u[2 * tid] >> 7) & 0xFF;
        unsigned long long bad = __ballot(e0 >= 0x90);
        if (tid == 0) *p.flag = (__popcll(bad) > 2) ? 0 : 1;  // 1=bf16, 0=f32
    }
}

// ---------------- P1: prelude (deg count + s init + weight prep) ----------------
__device__ void phase_prelude(const KParams& p, int isbf) {
    const int N128 = p.N * 128;
    const int NW1 = 3 * 4 * 8 * 64;
    const int NW2 = 3 * 4 * 24 * 64;
    const int NWT = 3 * 384;
    int tot = (N128 > p.E) ? N128 : p.E;
    for (int idx = blockIdx.x * 256 + threadIdx.x; idx < tot; idx += gridDim.x * 256) {
        if (idx < p.E) {
            int i = p.nbr[2 * idx], j = p.nbr[2 * idx + 1];
            float dx = ldin(p.xyz, 3 * j,     isbf) - ldin(p.xyz, 3 * i,     isbf);
            float dy = ldin(p.xyz, 3 * j + 1, isbf) - ldin(p.xyz, 3 * i + 1, isbf);
            float dz = ldin(p.xyz, 3 * j + 2, isbf) - ldin(p.xyz, 3 * i + 2, isbf);
            float dist = sqrtf(dx * dx + dy * dy + dz * dz + 3e-15f);
            if (dist < 5.0f) atomicAdd(&p.deg[i], 1);
        }
        if (idx < N128) {
            float v = ldin(p.cg_s, idx, isbf);
            p.s_acc[idx] = v;
            ushort_t hi = f2bf(v);
            p.s_hi[idx] = hi;
            p.s_lo[idx] = f2bf(v - bf2f(hi));
        }
        if (idx < NW1) {
            int lane = idx & 63;
            int t = idx >> 6;
            int nt = t % 8; t /= 8;
            int ks = t % 4; int l = t / 4;
            int n = lane & 15, quad = lane >> 4;
            int col = nt * 16 + n;
            size_t base = (size_t)l * 128 * 128;
            size_t fo = (size_t)idx * 8;
            #pragma unroll
            for (int j = 0; j < 8; j++) {
                int k = ks * 32 + quad * 8 + j;
                float v = ldin(p.W1, base + (size_t)k * 128 + col, isbf);
                ushort_t hi = f2bf(v);
                p.B1hi[fo + j] = hi;
                p.B1lo[fo + j] = f2bf(v - bf2f(hi));
            }
        } else if (idx < NW1 + NW2) {
            int i2 = idx - NW1;
            int lane = i2 & 63;
            int t = i2 >> 6;
            int nt = t % 24; t /= 24;
            int ks = t % 4; int l = t / 4;
            int n = lane & 15, quad = lane >> 4;
            int col = nt * 16 + n;
            size_t base = (size_t)l * 128 * 384;
            size_t fo = (size_t)i2 * 8;
            #pragma unroll
            for (int j = 0; j < 8; j++) {
                int k = ks * 32 + quad * 8 + j;
                float v = ldin(p.W2, base + (size_t)k * 384 + col, isbf);
                ushort_t hi = f2bf(v);
                p.B2hi[fo + j] = hi;
                p.B2lo[fo + j] = f2bf(v - bf2f(hi));
            }
        } else if (idx < NW1 + NW2 + NWT) {
            int i2 = idx - NW1 - NW2;
            int l = i2 / 384, col = i2 % 384;
            _Float16* wt = p.WrT + ((size_t)l * 384 + col) * KAUG;
            #pragma unroll
            for (int k = 0; k < KAUG; k++) {
                float v = 0.f;
                if (k < NRBF) v = ldin(p.Wr, ((size_t)l * NRBF + k) * 384 + col, isbf);
                else if (k == NRBF) v = ldin(p.br, (size_t)l * 384 + col, isbf);
                wt[k] = (_Float16)v;
            }
        }
    }
}

// ---------------- scan (block-0 work item): rowptr from deg; deg becomes cursor ----
__device__ void scan_block(const KParams& p) {
    __shared__ int part[256];
    int t = threadIdx.x;
    int N = p.N;
    int chunk = (N + 255) / 256;
    int lo = t * chunk, hi = min(lo + chunk, N);
    int s = 0;
    for (int i = lo; i < hi; i++) s += p.deg[i];
    part[t] = s;
    __syncthreads();
    for (int off = 1; off < 256; off <<= 1) {
        int v = (t >= off) ? part[t - off] : 0;
        __syncthreads();
        if (t >= off) part[t] += v;
        __syncthreads();
    }
    int base = (t == 0) ? 0 : part[t - 1];
    for (int i = lo; i < hi; i++) {
        p.rowptr[i] = base;
        int d = p.deg[i];
        p.deg[i] = base;
        base += d;
    }
    if (t == 0) p.rowptr[N] = part[255];
}

// ---------------- pack work item (256 edges): geometry + CSR scatter -------------
__device__ void pack_edge(const KParams& p, int isbf, int e) {
    if (e >= p.E) return;
    int i = p.nbr[2 * e], j = p.nbr[2 * e + 1];
    float dx = ldin(p.xyz, 3 * j,     isbf) - ldin(p.xyz, 3 * i,     isbf);
    float dy = ldin(p.xyz, 3 * j + 1, isbf) - ldin(p.xyz, 3 * i + 1, isbf);
    float dz = ldin(p.xyz, 3 * j + 2, isbf) - ldin(p.xyz, 3 * i + 2, isbf);
    float dist = sqrtf(dx * dx + dy * dy + dz * dz + 3e-15f);
    if (!(dist < 5.0f)) return;
    constexpr float PI = 3.14159265358979323846f;
    float ev = 0.5f * (cosf(PI * dist * 0.2f) + 1.0f);
    int pos = atomicAdd(&p.deg[i], 1);
    p.jlist[pos] = j;
    float inv = 1.0f / dist;
    p.upos[pos] = make_float4(dx * inv, dy * inv, dz * inv, ev);
    constexpr double EM5 = 0.006737946999085467;  // exp(-5)
    constexpr float MU0 = (float)EM5;
    constexpr float DMU = (float)((1.0 - EM5) / 19.0);
    constexpr float BETA = (float)(1.0 / ((0.1 * (1.0 - EM5)) * (0.1 * (1.0 - EM5))));
    float ed = expf(-dist);
    _Float16* rp = p.rbfh + (size_t)pos * KAUG;
    #pragma unroll
    for (int k = 0; k < NRBF; k++) {
        float dmu = ed - (MU0 + k * DMU);
        rp[k] = (_Float16)(ev * expf(-BETA * dmu * dmu));
    }
    rp[NRBF] = (_Float16)ev;
    #pragma unroll
    for (int k = NRBF + 1; k < KAUG; k++) rp[k] = (_Float16)0.f;
}

// ---------------- MFMA GEMM work item (one 64-row x 16-col tile group) ----------
template <int ACT, int OUTMODE, int NTILES>
__device__ __forceinline__ void gemm_item(
    int item, const ushort_t* __restrict__ Ahi, const ushort_t* __restrict__ Alo,
    const ushort_t* __restrict__ Bhi, const ushort_t* __restrict__ Blo,
    const void* __restrict__ bias, size_t biasoff,
    ushort_t* __restrict__ out_hi, ushort_t* __restrict__ out_lo,
    int M, int isbf) {
    constexpr int Ncols = NTILES * 16;
    int nt = item % NTILES;
    int bx = item / NTILES;
    int tid = threadIdx.x;
    int wave = tid >> 6, lane = tid & 63;
    int m = lane & 15, quad = lane >> 4;
    int brow = bx * 64 + wave * 16;
    int row = brow + m;
    float4v acc = {};
    short8 zero8 = {};
    #pragma unroll
    for (int ks = 0; ks < 4; ks++) {
        short8 ah = zero8, al = zero8;
        if (row < M) {
            size_t ao = (size_t)row * 128 + ks * 32 + quad * 8;
            ah = *reinterpret_cast<const short8*>(Ahi + ao);
            al = *reinterpret_cast<const short8*>(Alo + ao);
        }
        size_t fo = (((size_t)ks * NTILES + nt) * 64 + lane) * 8;
        short8 bh = *reinterpret_cast<const short8*>(Bhi + fo);
        acc = __builtin_amdgcn_mfma_f32_16x16x32_bf16(ah, bh, acc, 0, 0, 0);
        acc = __builtin_amdgcn_mfma_f32_16x16x32_bf16(al, bh, acc, 0, 0, 0);
        if (!isbf) {
            short8 bl = *reinterpret_cast<const short8*>(Blo + fo);
            acc = __builtin_amdgcn_mfma_f32_16x16x32_bf16(ah, bl, acc, 0, 0, 0);
        }
    }
    int col = nt * 16 + m;
    float bv = ldin(bias, biasoff + col, isbf);
    #pragma unroll
    for (int r = 0; r < 4; r++) {
        int orow = brow + quad * 4 + r;
        if (orow >= M) continue;
        float x = acc[r] + bv;
        if (ACT) x = x / (1.0f + expf(-x));  // silu
        size_t oo = (size_t)orow * Ncols + col;
        ushort_t h = f2bf(x);
        out_hi[oo] = h;
        if (OUTMODE == 0) out_lo[oo] = f2bf(x - bf2f(h));
    }
}

// ---------------- gemm1 phase (optionally hosting the scan at item 0) ----------
__device__ void phase_g1(const KParams& p, int isbf, int l, bool withScan) {
    const ushort_t* Bh = p.B1hi + (size_t)l * 4 * 8 * 64 * 8;
    const ushort_t* Bl = p.B1lo + (size_t)l * 4 * 8 * 64 * 8;
    size_t boff = (size_t)l * 128;
    int g1 = p.gx * 8;
    int items = g1 + (withScan ? 1 : 0);
    for (int it = blockIdx.x; it < items; it += gridDim.x) {
        if (withScan) {
            if (it == 0) { scan_block(p); continue; }
            gemm_item<1, 0, 8>(it - 1, p.s_hi, p.s_lo, Bh, Bl, p.b1, boff,
                               p.h_hi, p.h_lo, p.N, isbf);
        } else {
            gemm_item<1, 0, 8>(it, p.s_hi, p.s_lo, Bh, Bl, p.b1, boff,
                               p.h_hi, p.h_lo, p.N, isbf);
        }
    }
}

// ---------------- gemm2 phase (optionally hosting pack items after it) ----------
__device__ void phase_g2(const KParams& p, int isbf, int l, bool withPack) {
    const ushort_t* Bh = p.B2hi + (size_t)l * 4 * 24 * 64 * 8;
    const ushort_t* Bl = p.B2lo + (size_t)l * 4 * 24 * 64 * 8;
    size_t boff = (size_t)l * 384;
    int g2 = p.gx * 24;
    int packItems = withPack ? (p.E + 255) / 256 : 0;
    int items = g2 + packItems;
    for (int it = blockIdx.x; it < items; it += gridDim.x) {
        if (it < g2) {
            gemm_item<0, 1, 24>(it, p.h_hi, p.h_lo, Bh, Bl, p.b2, boff,
                                p.phi, (ushort_t*)nullptr, p.N, isbf);
        } else {
            pack_edge(p, isbf, (it - g2) * 256 + threadIdx.x);
        }
    }
}

// ---------------- node phase: 2 nodes per 256-thread block item ----------------
// WrT hoist done ONCE per phase (amortized over ~items/grid nodes per block).
template <int L0, int LAST>
__device__ void phase_node(const KParams& p, int isbf, const _Float16* WrTl,
                           const float* v_old, const ushort_t* vh_old,
                           float* v_new, ushort_t* vh_new) {
    int tid = threadIdx.x;
    int half = tid >> 7;
    int tt = tid & 127;

    F4H wc0[3], wc1[3], wc2[3];
    {
        const float4v* w0p = (const float4v*)(WrTl + (size_t)tt * KAUG);
        const float4v* w1p = (const float4v*)(WrTl + (size_t)(tt + 128) * KAUG);
        const float4v* w2p = (const float4v*)(WrTl + (size_t)(tt + 256) * KAUG);
        #pragma unroll
        for (int r = 0; r < 3; r++) {
            wc0[r].f = w0p[r]; wc1[r].f = w1p[r]; wc2[r].f = w2p[r];
        }
    }
    int items = (p.N + 1) >> 1;
    for (int it = blockIdx.x; it < items; it += gridDim.x) {
        int node = it * 2 + half;
        if (node >= p.N) continue;
        int start = __builtin_amdgcn_readfirstlane(p.rowptr[node]);
        int end   = __builtin_amdgcn_readfirstlane(p.rowptr[node + 1]);

        float dsv = 0.f, ax = 0.f, ay = 0.f, az = 0.f;
        int j = (start < end) ? __builtin_amdgcn_readfirstlane(p.jlist[start]) : 0;
        for (int k = start; k < end; k++) {
            int jn = j;
            if (k + 1 < end) jn = __builtin_amdgcn_readfirstlane(p.jlist[k + 1]);
            float4 u4 = p.upos[k];
            const float4v* rp4 = (const float4v*)(p.rbfh + (size_t)k * KAUG);
            F4H rv0, rv1, rv2;
            rv0.f = rp4[0]; rv1.f = rp4[1]; rv2.f = rp4[2];
            float w0 = 0.f, w1 = 0.f, w2 = 0.f;
            #pragma unroll
            for (int q = 0; q < 4; q++) {
                w0 = dot2(rv0.h[q], wc0[0].h[q], w0);
                w1 = dot2(rv0.h[q], wc1[0].h[q], w1);
                w2 = dot2(rv0.h[q], wc2[0].h[q], w2);
            }
            #pragma unroll
            for (int q = 0; q < 4; q++) {
                w0 = dot2(rv1.h[q], wc0[1].h[q], w0);
                w1 = dot2(rv1.h[q], wc1[1].h[q], w1);
                w2 = dot2(rv1.h[q], wc2[1].h[q], w2);
            }
            #pragma unroll
            for (int q = 0; q < 4; q++) {
                w0 = dot2(rv2.h[q], wc0[2].h[q], w0);
                w1 = dot2(rv2.h[q], wc1[2].h[q], w1);
                w2 = dot2(rv2.h[q], wc2[2].h[q], w2);
            }
            size_t jb = (size_t)j * 384;
            dsv += bf2f(p.phi[jb + tt]) * w0;
            float gv = bf2f(p.phi[jb + 128 + tt]) * w1;
            float gu = bf2f(p.phi[jb + 256 + tt]) * w2;
            if (L0) {
                ax += gu * u4.x; ay += gu * u4.y; az += gu * u4.z;
            } else {
                const ushort_t* vj = &vh_old[jb + (size_t)tt * 3];
                ax += gu * u4.x + gv * bf2f(vj[0]);
                ay += gu * u4.y + gv * bf2f(vj[1]);
                az += gu * u4.z + gv * bf2f(vj[2]);
            }
            j = jn;
        }
        size_t so = (size_t)node * 128 + tt;
        float snew = p.s_acc[so] + dsv;
        size_t ib = (size_t)node * 384 + (size_t)tt * 3;
        float vx = L0 ? ax : v_old[ib]     + ax;
        float vy = L0 ? ay : v_old[ib + 1] + ay;
        float vz = L0 ? az : v_old[ib + 2] + az;
        if (LAST) {
            stout(p.out, so, snew, isbf);
            size_t ob = (size_t)p.N * 128 + ib;
            stout(p.out, ob,     vx, isbf);
            stout(p.out, ob + 1, vy, isbf);
            stout(p.out, ob + 2, vz, isbf);
        } else {
            p.s_acc[so] = snew;
            ushort_t hi = f2bf(snew);
            p.s_hi[so] = hi;
            p.s_lo[so] = f2bf(snew - bf2f(hi));
            v_new[ib] = vx; v_new[ib + 1] = vy; v_new[ib + 2] = vz;
            vh_new[ib]     = f2bf(vx);
            vh_new[ib + 1] = f2bf(vy);
            vh_new[ib + 2] = f2bf(vz);
        }
    }
}

// ---------------- the single cooperative mega-kernel ----------------
// 11 phases, 10 grid syncs, replaces 13 serial launches. scan overlaps
// gemm1(l0); pack overlaps gemm2(l0). All phase arithmetic identical to the
// split-kernel version -> bit-identical output.
__global__ __launch_bounds__(256, 4) void mega_kernel(KParams p) {
    cg::grid_group grid = cg::this_grid();

    phase_detect(p);
    grid.sync();
    int isbf = *p.flag;
    phase_prelude(p, isbf);
    grid.sync();

    // layer 0
    phase_g1(p, isbf, 0, true);   // + scan on item 0
    grid.sync();
    phase_g2(p, isbf, 0, true);   // + pack items
    grid.sync();
    phase_node<1, 0>(p, isbf, p.WrT, p.vA, p.vhA, p.vA, p.vhA);
    grid.sync();
    // layer 1
    phase_g1(p, isbf, 1, false);
    grid.sync();
    phase_g2(p, isbf, 1, false);
    grid.sync();
    phase_node<0, 0>(p, isbf, p.WrT + (size_t)384 * KAUG, p.vA, p.vhA, p.vB, p.vhB);
    grid.sync();
    // layer 2
    phase_g1(p, isbf, 2, false);
    grid.sync();
    phase_g2(p, isbf, 2, false);
    grid.sync();
    phase_node<0, 1>(p, isbf, p.WrT + (size_t)2 * 384 * KAUG, p.vB, p.vhB, p.vB, p.vhB);
}

extern "C" void kernel_launch(void* const* d_in, const int* in_sizes, int n_in,
                              void* d_out, int out_size, void* d_ws, size_t ws_size,
                              hipStream_t stream) {
    const int N = in_sizes[0] / 3;
    const int E = in_sizes[1] / 2;

    size_t off = 0;
    auto alloc = [&](size_t bytes) -> char* {
        char* p = (char*)d_ws + off;
        off = (off + bytes + 63) & ~(size_t)63;
        return p;
    };
    KParams P;
    P.xyz  = d_in[0];
    P.nbr  = (const int*)d_in[1];
    P.cg_s = d_in[2];
    P.W1   = d_in[3];
    P.b1   = d_in[4];
    P.W2   = d_in[5];
    P.b2   = d_in[6];
    P.Wr   = d_in[7];
    P.br   = d_in[8];
    P.flag   = (int*)alloc(64);
    P.s_acc  = (float*)alloc((size_t)N * 128 * 4);
    P.vA     = (float*)alloc((size_t)N * 384 * 4);
    P.vB     = (float*)alloc((size_t)N * 384 * 4);
    P.rowptr = (int*)alloc((size_t)(N + 1) * 4);
    P.deg    = (int*)alloc((size_t)N * 4);
    P.jlist  = (int*)alloc((size_t)E * 4);
    P.upos   = (float4*)alloc((size_t)(E + 16) * 16);
    P.rbfh   = (_Float16*)alloc((size_t)(E + 16) * KAUG * 2);
    P.WrT    = (_Float16*)alloc((size_t)3 * 384 * KAUG * 2);
    P.s_hi   = (ushort_t*)alloc((size_t)N * 128 * 2);
    P.s_lo   = (ushort_t*)alloc((size_t)N * 128 * 2);
    P.h_hi   = (ushort_t*)alloc((size_t)N * 128 * 2);
    P.h_lo   = (ushort_t*)alloc((size_t)N * 128 * 2);
    P.phi    = (ushort_t*)alloc((size_t)N * 384 * 2);
    P.vhA    = (ushort_t*)alloc((size_t)N * 384 * 2);
    P.vhB    = (ushort_t*)alloc((size_t)N * 384 * 2);
    P.B1hi   = (ushort_t*)alloc((size_t)3 * 4 * 8 * 64 * 8 * 2);
    P.B1lo   = (ushort_t*)alloc((size_t)3 * 4 * 8 * 64 * 8 * 2);
    P.B2hi   = (ushort_t*)alloc((size_t)3 * 4 * 24 * 64 * 8 * 2);
    P.B2lo   = (ushort_t*)alloc((size_t)3 * 4 * 24 * 64 * 8 * 2);
    P.out = d_out;
    P.N = N;
    P.E = E;
    P.gx = (N + 63) / 64;

    // grid sized for guaranteed co-residency (occupancy API), cached once
    static int coopGrid = 0;
    if (coopGrid == 0) {
        int bpc = 0;
        if (hipOccupancyMaxActiveBlocksPerMultiprocessor(&bpc, mega_kernel, 256, 0)
                != hipSuccess || bpc < 1)
            bpc = 1;
        if (bpc > 8) bpc = 8;
        hipDeviceProp_t prop{};
        int dev = 0;
        hipGetDevice(&dev);
        int cus = (hipGetDeviceProperties(&prop, dev) == hipSuccess &&
                   prop.multiProcessorCount > 0) ? prop.multiProcessorCount : 256;
        coopGrid = bpc * cus;
    }

    void* args[] = { (void*)&P };
    hipLaunchCooperativeKernel(mega_kernel, dim3(coopGrid), dim3(256), args, 0, stream);
}

// Round 7
// 304.832 us; speedup vs baseline: 3.7306x; 3.7306x over previous
//
#include <hip/hip_runtime.h>
#include <hip/hip_bf16.h>

#define NRBF 20
#define KAUG 24   // 20 rbf + env(bias row) + 3 zero pad, stored f16
#define DMAX 64   // padded slots per node (deg ~ Poisson(<=16); P(>64) ~ 1e-19)

typedef __attribute__((ext_vector_type(8))) short short8;
typedef __attribute__((ext_vector_type(4))) float float4v;
typedef __attribute__((ext_vector_type(2))) _Float16 half2v;
typedef unsigned short ushort_t;

__device__ __forceinline__ float bf2f(ushort_t u) {
    return __uint_as_float(((unsigned)u) << 16);
}
__device__ __forceinline__ ushort_t f2bf(float f) {
    unsigned u = __float_as_uint(f);
    u += 0x7FFF + ((u >> 16) & 1);   // round-to-nearest-even
    return (ushort_t)(u >> 16);
}
__device__ __forceinline__ float ldin(const void* p, size_t idx, int isbf) {
    return isbf ? bf2f(((const ushort_t*)p)[idx]) : ((const float*)p)[idx];
}
__device__ __forceinline__ void stout(void* p, size_t idx, float v, int isbf) {
    if (isbf) ((ushort_t*)p)[idx] = f2bf(v);
    else      ((float*)p)[idx] = v;
}
__device__ __forceinline__ float dot2(half2v a, half2v b, float c) {
#if __has_builtin(__builtin_amdgcn_fdot2)
    return __builtin_amdgcn_fdot2(a, b, c, false);
#else
    return c + (float)a.x * (float)b.x + (float)a.y * (float)b.y;
#endif
}

// view a 16B float4 register quad as 4 half2 lanes (free re-alias, no moves)
union F4H {
    float4v f;
    half2v  h[4];
};

// ---------------- dtype detect + cursor zero (fused) ----------------
__global__ void detect_kernel(const void* __restrict__ xyz, int* __restrict__ flag,
                              int* __restrict__ cursor, int N) {
    int idx = blockIdx.x * blockDim.x + threadIdx.x;
    if (idx < N) cursor[idx] = 0;
    if (blockIdx.x == 0 && threadIdx.x < 64) {
        const ushort_t* u = (const ushort_t*)xyz;
        unsigned e0 = (u[2 * threadIdx.x] >> 7) & 0xFF;
        unsigned long long bad = __ballot(e0 >= 0x90);
        if (threadIdx.x == 0) *flag = (__popcll(bad) > 2) ? 0 : 1;  // 1=bf16, 0=f32
    }
}

// ---------------- fused prep kernel ----------------
// Replaces prelude + scan + pack (3 dispatches -> 1).
// - NO deg-count pass, NO prefix scan: padded CSR (DMAX slots/node), pack
//   claims a slot with atomicAdd(cursor[i]) directly.
// - also: s init, W1/W2 MFMA-fragment prep, WrT transpose (unchanged math).
__global__ void prep_kernel(const void* __restrict__ xyz, const int* __restrict__ nbr,
                            const void* __restrict__ cg_s,
                            const void* __restrict__ W1, const void* __restrict__ W2,
                            const void* __restrict__ Wr, const void* __restrict__ br,
                            float* __restrict__ s_acc, ushort_t* __restrict__ s_hi,
                            ushort_t* __restrict__ s_lo, int* __restrict__ cursor,
                            int* __restrict__ jlist, float4* __restrict__ upos,
                            _Float16* __restrict__ rbfh,
                            ushort_t* __restrict__ B1hi, ushort_t* __restrict__ B1lo,
                            ushort_t* __restrict__ B2hi, ushort_t* __restrict__ B2lo,
                            _Float16* __restrict__ WrT,
                            int N128, int E, const int* __restrict__ flagp) {
    int isbf = *flagp;
    int idx = blockIdx.x * blockDim.x + threadIdx.x;

    // ---- edge pack (padded CSR) ----
    if (idx < E) {
        int i = nbr[2 * idx], j = nbr[2 * idx + 1];
        float dx = ldin(xyz, 3 * j,     isbf) - ldin(xyz, 3 * i,     isbf);
        float dy = ldin(xyz, 3 * j + 1, isbf) - ldin(xyz, 3 * i + 1, isbf);
        float dz = ldin(xyz, 3 * j + 2, isbf) - ldin(xyz, 3 * i + 2, isbf);
        float dist = sqrtf(dx * dx + dy * dy + dz * dz + 3e-15f);
        if (dist < 5.0f) {
            constexpr float PI = 3.14159265358979323846f;
            float ev = 0.5f * (cosf(PI * dist * 0.2f) + 1.0f);
            int c = atomicAdd(&cursor[i], 1);
            if (c < DMAX) {
                size_t pos = (size_t)i * DMAX + c;
                jlist[pos] = j;
                float inv = 1.0f / dist;
                upos[pos] = make_float4(dx * inv, dy * inv, dz * inv, ev);
                constexpr double EM5 = 0.006737946999085467;  // exp(-5)
                constexpr float MU0 = (float)EM5;
                constexpr float DMU = (float)((1.0 - EM5) / 19.0);
                constexpr float BETA =
                    (float)(1.0 / ((0.1 * (1.0 - EM5)) * (0.1 * (1.0 - EM5))));
                float ed = expf(-dist);
                _Float16* rp = rbfh + pos * KAUG;
                #pragma unroll
                for (int k = 0; k < NRBF; k++) {
                    float dmu = ed - (MU0 + k * DMU);
                    rp[k] = (_Float16)(ev * expf(-BETA * dmu * dmu));
                }
                rp[NRBF] = (_Float16)ev;
                #pragma unroll
                for (int k = NRBF + 1; k < KAUG; k++) rp[k] = (_Float16)0.f;
            }
        }
    }
    // ---- s init ----
    if (idx < N128) {
        float v = ldin(cg_s, idx, isbf);
        s_acc[idx] = v;
        ushort_t hi = f2bf(v);
        s_hi[idx] = hi;
        s_lo[idx] = f2bf(v - bf2f(hi));
    }
    // ---- weight prep ----
    const int NW1 = 3 * 4 * 8 * 64;
    const int NW2 = 3 * 4 * 24 * 64;
    const int NWT = 3 * 384;
    if (idx < NW1) {
        int lane = idx & 63;
        int t = idx >> 6;
        int nt = t % 8; t /= 8;
        int ks = t % 4; int l = t / 4;
        int n = lane & 15, quad = lane >> 4;
        int col = nt * 16 + n;
        size_t base = (size_t)l * 128 * 128;
        size_t fo = (size_t)idx * 8;
        #pragma unroll
        for (int j = 0; j < 8; j++) {
            int k = ks * 32 + quad * 8 + j;
            float v = ldin(W1, base + (size_t)k * 128 + col, isbf);
            ushort_t hi = f2bf(v);
            B1hi[fo + j] = hi;
            B1lo[fo + j] = f2bf(v - bf2f(hi));
        }
    } else if (idx < NW1 + NW2) {
        int i2 = idx - NW1;
        int lane = i2 & 63;
        int t = i2 >> 6;
        int nt = t % 24; t /= 24;
        int ks = t % 4; int l = t / 4;
        int n = lane & 15, quad = lane >> 4;
        int col = nt * 16 + n;
        size_t base = (size_t)l * 128 * 384;
        size_t fo = (size_t)i2 * 8;
        #pragma unroll
        for (int j = 0; j < 8; j++) {
            int k = ks * 32 + quad * 8 + j;
            float v = ldin(W2, base + (size_t)k * 384 + col, isbf);
            ushort_t hi = f2bf(v);
            B2hi[fo + j] = hi;
            B2lo[fo + j] = f2bf(v - bf2f(hi));
        }
    } else if (idx < NW1 + NW2 + NWT) {
        int i2 = idx - NW1 - NW2;
        int l = i2 / 384, col = i2 % 384;
        _Float16* wt = WrT + ((size_t)l * 384 + col) * KAUG;
        #pragma unroll
        for (int k = 0; k < KAUG; k++) {
            float v = 0.f;
            if (k < NRBF) v = ldin(Wr, ((size_t)l * NRBF + k) * 384 + col, isbf);
            else if (k == NRBF) v = ldin(br, (size_t)l * 384 + col, isbf);
            wt[k] = (_Float16)v;
        }
    }
}

// ---------------- MFMA GEMM, 1D swizzled grid for A-locality ----------------
// grid = ceil(M/64) * NTILES, 1D: nt = idx % NTILES (fast), bx = idx / NTILES
// -> consecutive blocks share the same 64 A-rows (L1/L2-hot); B frags are small.
template <int ACT, int OUTMODE, int NTILES>
__global__ __launch_bounds__(256) void mfma_gemm(
    const ushort_t* __restrict__ Ahi, const ushort_t* __restrict__ Alo,
    const ushort_t* __restrict__ Bhi, const ushort_t* __restrict__ Blo,
    const void* __restrict__ bias, size_t biasoff,
    ushort_t* __restrict__ out_hi, ushort_t* __restrict__ out_lo,
    int M, const int* __restrict__ flagp) {
    constexpr int Ncols = NTILES * 16;
    int isbf = *flagp;
    int nt = blockIdx.x % NTILES;
    int bx = blockIdx.x / NTILES;
    int tid = threadIdx.x;
    int wave = tid >> 6, lane = tid & 63;
    int m = lane & 15, quad = lane >> 4;
    int brow = bx * 64 + wave * 16;
    int row = brow + m;
    float4v acc = {};
    short8 zero8 = {};
    #pragma unroll
    for (int ks = 0; ks < 4; ks++) {
        short8 ah = zero8, al = zero8;
        if (row < M) {
            size_t ao = (size_t)row * 128 + ks * 32 + quad * 8;
            ah = *reinterpret_cast<const short8*>(Ahi + ao);
            al = *reinterpret_cast<const short8*>(Alo + ao);
        }
        size_t fo = (((size_t)ks * NTILES + nt) * 64 + lane) * 8;
        short8 bh = *reinterpret_cast<const short8*>(Bhi + fo);
        acc = __builtin_amdgcn_mfma_f32_16x16x32_bf16(ah, bh, acc, 0, 0, 0);
        acc = __builtin_amdgcn_mfma_f32_16x16x32_bf16(al, bh, acc, 0, 0, 0);
        if (!isbf) {
            short8 bl = *reinterpret_cast<const short8*>(Blo + fo);
            acc = __builtin_amdgcn_mfma_f32_16x16x32_bf16(ah, bl, acc, 0, 0, 0);
        }
    }
    int col = nt * 16 + m;
    float bv = ldin(bias, biasoff + col, isbf);
    #pragma unroll
    for (int r = 0; r < 4; r++) {
        int orow = brow + quad * 4 + r;
        if (orow >= M) continue;
        float x = acc[r] + bv;
        if (ACT) x = x / (1.0f + expf(-x));  // silu
        size_t oo = (size_t)orow * Ncols + col;
        ushort_t h = f2bf(x);
        out_hi[oo] = h;
        if (OUTMODE == 0) out_lo[oo] = f2bf(x - bf2f(h));
    }
}

// ---------------- node gather kernel (padded CSR) ----------
// One block per node, 128 threads; thread tt owns features {tt, 128+tt, 256+tt}.
// Padded layout: edge slots for node are [node*DMAX, node*DMAX+cnt) — start is
// SGPR arithmetic (no rowptr loads); cnt = cursor[node].
template <int L0, int LAST>
__global__ __launch_bounds__(128, 8) void node_kernel(
    const int* __restrict__ cursor, const int* __restrict__ jlist,
    const float4* __restrict__ upos, const _Float16* __restrict__ rbfh,
    const _Float16* __restrict__ WrT,
    const ushort_t* __restrict__ phi,
    const float* __restrict__ v_old, const ushort_t* __restrict__ vh_old,
    float* __restrict__ s_acc, ushort_t* __restrict__ s_hi, ushort_t* __restrict__ s_lo,
    float* __restrict__ v_new, ushort_t* __restrict__ vh_new,
    void* __restrict__ out, int N, const int* __restrict__ flagp) {
    int isbf = *flagp;
    int tt = threadIdx.x;
    int node = blockIdx.x;

    // hoist this thread's 3 WrT columns: 3 x float4 (48B) each, 9 loads total
    F4H wc0[3], wc1[3], wc2[3];
    {
        const float4v* w0p = (const float4v*)(WrT + (size_t)tt * KAUG);
        const float4v* w1p = (const float4v*)(WrT + (size_t)(tt + 128) * KAUG);
        const float4v* w2p = (const float4v*)(WrT + (size_t)(tt + 256) * KAUG);
        #pragma unroll
        for (int r = 0; r < 3; r++) {
            wc0[r].f = w0p[r]; wc1[r].f = w1p[r]; wc2[r].f = w2p[r];
        }
    }
    int cnt   = __builtin_amdgcn_readfirstlane(cursor[node]);
    if (cnt > DMAX) cnt = DMAX;
    int start = node * DMAX;
    int end   = start + cnt;

    float dsv = 0.f, ax = 0.f, ay = 0.f, az = 0.f;
    // scalar j prefetch: j for edge k is loaded during iteration k-1
    int j = (start < end) ? __builtin_amdgcn_readfirstlane(jlist[start]) : 0;
    for (int k = start; k < end; k++) {
        int jn = j;
        if (k + 1 < end) jn = __builtin_amdgcn_readfirstlane(jlist[k + 1]);
        float4 u4 = upos[k];
        const float4v* rp4 = (const float4v*)(rbfh + (size_t)k * KAUG);
        F4H rv0, rv1, rv2;
        rv0.f = rp4[0]; rv1.f = rp4[1]; rv2.f = rp4[2];
        float w0 = 0.f, w1 = 0.f, w2 = 0.f;
        #pragma unroll
        for (int q = 0; q < 4; q++) {
            w0 = dot2(rv0.h[q], wc0[0].h[q], w0);
            w1 = dot2(rv0.h[q], wc1[0].h[q], w1);
            w2 = dot2(rv0.h[q], wc2[0].h[q], w2);
        }
        #pragma unroll
        for (int q = 0; q < 4; q++) {
            w0 = dot2(rv1.h[q], wc0[1].h[q], w0);
            w1 = dot2(rv1.h[q], wc1[1].h[q], w1);
            w2 = dot2(rv1.h[q], wc2[1].h[q], w2);
        }
        #pragma unroll
        for (int q = 0; q < 4; q++) {
            w0 = dot2(rv2.h[q], wc0[2].h[q], w0);
            w1 = dot2(rv2.h[q], wc1[2].h[q], w1);
            w2 = dot2(rv2.h[q], wc2[2].h[q], w2);
        }
        size_t jb = (size_t)j * 384;
        dsv += bf2f(phi[jb + tt]) * w0;
        float gv = bf2f(phi[jb + 128 + tt]) * w1;
        float gu = bf2f(phi[jb + 256 + tt]) * w2;
        if (L0) {
            ax += gu * u4.x; ay += gu * u4.y; az += gu * u4.z;
        } else {
            const ushort_t* vj = &vh_old[jb + (size_t)tt * 3];
            ax += gu * u4.x + gv * bf2f(vj[0]);
            ay += gu * u4.y + gv * bf2f(vj[1]);
            az += gu * u4.z + gv * bf2f(vj[2]);
        }
        j = jn;
    }
    size_t so = (size_t)node * 128 + tt;
    float snew = s_acc[so] + dsv;
    size_t ib = (size_t)node * 384 + (size_t)tt * 3;
    float vx = L0 ? ax : v_old[ib]     + ax;
    float vy = L0 ? ay : v_old[ib + 1] + ay;
    float vz = L0 ? az : v_old[ib + 2] + az;
    if (LAST) {
        stout(out, so, snew, isbf);
        size_t ob = (size_t)N * 128 + ib;
        stout(out, ob,     vx, isbf);
        stout(out, ob + 1, vy, isbf);
        stout(out, ob + 2, vz, isbf);
    } else {
        s_acc[so] = snew;
        ushort_t hi = f2bf(snew);
        s_hi[so] = hi;
        s_lo[so] = f2bf(snew - bf2f(hi));
        v_new[ib] = vx; v_new[ib + 1] = vy; v_new[ib + 2] = vz;
        vh_new[ib]     = f2bf(vx);
        vh_new[ib + 1] = f2bf(vy);
        vh_new[ib + 2] = f2bf(vz);
    }
}

extern "C" void kernel_launch(void* const* d_in, const int* in_sizes, int n_in,
                              void* d_out, int out_size, void* d_ws, size_t ws_size,
                              hipStream_t stream) {
    const int N = in_sizes[0] / 3;
    const int E = in_sizes[1] / 2;
    const void* xyz  = d_in[0];
    const int*  nbr  = (const int*)d_in[1];
    const void* cg_s = d_in[2];
    const void* W1   = d_in[3];
    const void* b1   = d_in[4];
    const void* W2   = d_in[5];
    const void* b2   = d_in[6];
    const void* Wr   = d_in[7];
    const void* br   = d_in[8];

    size_t off = 0;
    auto alloc = [&](size_t bytes) -> char* {
        char* p = (char*)d_ws + off;
        off = (off + bytes + 63) & ~(size_t)63;
        return p;
    };
    int*       flag   = (int*)alloc(64);
    float*     s_acc  = (float*)alloc((size_t)N * 128 * 4);
    float*     vA     = (float*)alloc((size_t)N * 384 * 4);
    float*     vB     = (float*)alloc((size_t)N * 384 * 4);
    int*       cursor = (int*)alloc((size_t)N * 4);
    int*       jlist  = (int*)alloc((size_t)N * DMAX * 4);
    float4*    upos   = (float4*)alloc((size_t)N * DMAX * 16);
    _Float16*  rbfh   = (_Float16*)alloc((size_t)N * DMAX * KAUG * 2);
    _Float16*  WrT    = (_Float16*)alloc((size_t)3 * 384 * KAUG * 2);
    ushort_t*  s_hi   = (ushort_t*)alloc((size_t)N * 128 * 2);
    ushort_t*  s_lo   = (ushort_t*)alloc((size_t)N * 128 * 2);
    ushort_t*  h_hi   = (ushort_t*)alloc((size_t)N * 128 * 2);
    ushort_t*  h_lo   = (ushort_t*)alloc((size_t)N * 128 * 2);
    ushort_t*  phi    = (ushort_t*)alloc((size_t)N * 384 * 2);
    ushort_t*  vhA    = (ushort_t*)alloc((size_t)N * 384 * 2);
    ushort_t*  vhB    = (ushort_t*)alloc((size_t)N * 384 * 2);
    ushort_t*  B1hi   = (ushort_t*)alloc((size_t)3 * 4 * 8 * 64 * 8 * 2);
    ushort_t*  B1lo   = (ushort_t*)alloc((size_t)3 * 4 * 8 * 64 * 8 * 2);
    ushort_t*  B2hi   = (ushort_t*)alloc((size_t)3 * 4 * 24 * 64 * 8 * 2);
    ushort_t*  B2lo   = (ushort_t*)alloc((size_t)3 * 4 * 24 * 64 * 8 * 2);

    detect_kernel<<<(N + 255) / 256, 256, 0, stream>>>(xyz, flag, cursor, N);

    const int N128 = N * 128;
    const int pg = (max(E, N128) + 255) / 256;
    prep_kernel<<<pg, 256, 0, stream>>>(xyz, nbr, cg_s, W1, W2, Wr, br,
                                        s_acc, s_hi, s_lo, cursor,
                                        jlist, upos, rbfh,
                                        B1hi, B1lo, B2hi, B2lo, WrT,
                                        N128, E, flag);

    const int gx = (N + 63) / 64;
    for (int l = 0; l < 3; l++) {
        mfma_gemm<1, 0, 8><<<gx * 8, 256, 0, stream>>>(
            s_hi, s_lo,
            B1hi + (size_t)l * 4 * 8 * 64 * 8, B1lo + (size_t)l * 4 * 8 * 64 * 8,
            b1, (size_t)l * 128, h_hi, h_lo, N, flag);
        mfma_gemm<0, 1, 24><<<gx * 24, 256, 0, stream>>>(
            h_hi, h_lo,
            B2hi + (size_t)l * 4 * 24 * 64 * 8, B2lo + (size_t)l * 4 * 24 * 64 * 8,
            b2, (size_t)l * 384, phi, (ushort_t*)nullptr, N, flag);
        const _Float16* wrt = WrT + (size_t)l * 384 * KAUG;
        if (l == 0) {
            node_kernel<1, 0><<<N, 128, 0, stream>>>(
                cursor, jlist, upos, rbfh, wrt, phi,
                vA, vhA, s_acc, s_hi, s_lo, vA, vhA, d_out, N, flag);
        } else if (l == 1) {
            node_kernel<0, 0><<<N, 128, 0, stream>>>(
                cursor, jlist, upos, rbfh, wrt, phi,
                vA, vhA, s_acc, s_hi, s_lo, vB, vhB, d_out, N, flag);
        } else {
            node_kernel<0, 1><<<N, 128, 0, stream>>>(
                cursor, jlist, upos, rbfh, wrt, phi,
                vB, vhB, s_acc, s_hi, s_lo, vB, vhB, d_out, N, flag);
        }
    }
}